// Round 1
// baseline (304.736 us; speedup 1.0000x reference)
//
#include <hip/hip_runtime.h>

#define BATCH   32
#define IN_DIM  2048
#define OUT_DIM 2048
#define ZDIM    64
#define NNZ     209715

// One thread per nonzero k.
//   e[b] = z[b,:] . W[:,k] + b_net[k]
//   out[b, out_idx[k]] += e[b] * x[b, in_idx[k]]
__global__ __launch_bounds__(256) void hyper_scatter_kernel(
    const float* __restrict__ x,      // [B, IN_DIM]
    const float* __restrict__ z,      // [B, ZDIM]
    const float* __restrict__ W,      // [ZDIM, NNZ]
    const float* __restrict__ bn,     // [NNZ]
    const int*   __restrict__ in_idx, // [NNZ]
    const int*   __restrict__ out_idx,// [NNZ]
    float*       __restrict__ out)    // [B, OUT_DIM] (pre-zeroed)
{
    __shared__ float zs[BATCH * ZDIM];   // 8 KB

    const int tid = threadIdx.x;

    // Stage z into LDS (2048 floats = 512 float4; 256 threads -> 2 each).
    {
        const float4* zg  = reinterpret_cast<const float4*>(z);
        float4*       zsv = reinterpret_cast<float4*>(zs);
        zsv[tid]       = zg[tid];
        zsv[tid + 256] = zg[tid + 256];
    }
    __syncthreads();

    const int k = blockIdx.x * 256 + tid;
    if (k >= NNZ) return;

    // Load the W column for this k: 64 coalesced loads (stride NNZ in j,
    // contiguous in k across lanes).
    float w[ZDIM];
    #pragma unroll
    for (int j = 0; j < ZDIM; ++j)
        w[j] = W[(size_t)j * NNZ + k];

    const float bk = bn[k];
    const int   ii = in_idx[k];
    const int   oi = out_idx[k];

    const float4* zv = reinterpret_cast<const float4*>(zs);

    #pragma unroll
    for (int b = 0; b < BATCH; ++b) {
        float e = bk;
        #pragma unroll
        for (int j4 = 0; j4 < ZDIM / 4; ++j4) {
            // Uniform LDS address across lanes -> broadcast, conflict-free.
            const float4 zz = zv[b * (ZDIM / 4) + j4];
            e = fmaf(zz.x, w[j4 * 4 + 0], e);
            e = fmaf(zz.y, w[j4 * 4 + 1], e);
            e = fmaf(zz.z, w[j4 * 4 + 2], e);
            e = fmaf(zz.w, w[j4 * 4 + 3], e);
        }
        const float xv = x[b * IN_DIM + ii];          // L2-resident gather
        atomicAdd(&out[b * OUT_DIM + oi], e * xv);    // device-scope f32 add
    }
}

extern "C" void kernel_launch(void* const* d_in, const int* in_sizes, int n_in,
                              void* d_out, int out_size, void* d_ws, size_t ws_size,
                              hipStream_t stream) {
    const float* x       = (const float*)d_in[0];
    const float* z       = (const float*)d_in[1];
    const float* W       = (const float*)d_in[2];
    const float* bn      = (const float*)d_in[3];
    const int*   in_idx  = (const int*)d_in[4];
    const int*   out_idx = (const int*)d_in[5];
    float*       out     = (float*)d_out;

    // d_out is poisoned (0xAA) and never re-poisoned between replays:
    // zero it every call before the scatter-accumulate.
    hipMemsetAsync(out, 0, (size_t)BATCH * OUT_DIM * sizeof(float), stream);

    const int grid = (NNZ + 255) / 256;  // 820 blocks
    hyper_scatter_kernel<<<grid, 256, 0, stream>>>(x, z, W, bn, in_idx, out_idx, out);
}

// Round 2
// 133.844 us; speedup vs baseline: 2.2768x; 2.2768x over previous
//
#include <hip/hip_runtime.h>

#define BATCH   32
#define IN_DIM  2048
#define OUT_DIM 2048
#define ZDIM    64
#define NNZ     209715

// ---------------- workspace layout (byte offsets, 16B-aligned) ----------------
// cnt : int[2048]          @ 0
// rp  : int[2049]          @ 8192
// cur : int[2048]          @ 16448
// xT  : float[2048*32]     @ 24640      (x transposed: xT[i*32+b])
// E   : float[NNZ*32]      @ 286784     (E[pos*32+b] = e[b,k(pos)] * x[b,in_idx])
#define OFF_CNT 0
#define OFF_RP  8192
#define OFF_CUR 16448
#define OFF_XT  24640
#define OFF_E   286784
#define WS_NEEDED (OFF_E + (size_t)NNZ * BATCH * sizeof(float))

// ---- stage 1: histogram of out_idx + transpose x into xT ----
__global__ __launch_bounds__(256) void hist_kernel(
    const int* __restrict__ out_idx, const float* __restrict__ x,
    int* __restrict__ cnt, float* __restrict__ xT)
{
    const int k = blockIdx.x * 256 + threadIdx.x;
    if (k < NNZ) atomicAdd(&cnt[out_idx[k]], 1);
    if (k < BATCH * IN_DIM) {
        const int b = k >> 11;        // /2048
        const int i = k & 2047;       // %2048
        xT[i * BATCH + b] = x[k];     // coalesced read, scattered write (L2)
    }
}

// ---- stage 2: exclusive scan of 2048 bins -> rp[2049], cur[2048] ----
__global__ __launch_bounds__(1024) void scan_kernel(
    const int* __restrict__ cnt, int* __restrict__ rp, int* __restrict__ cur)
{
    __shared__ int s[1024];
    const int t = threadIdx.x;
    const int c0 = cnt[2 * t], c1 = cnt[2 * t + 1];
    const int pair = c0 + c1;
    int val = pair;
    s[t] = val;
    __syncthreads();
    for (int off = 1; off < 1024; off <<= 1) {
        const int add = (t >= off) ? s[t - off] : 0;
        __syncthreads();
        val += add;
        s[t] = val;
        __syncthreads();
    }
    const int ex = val - pair;  // exclusive prefix over pairs
    rp[2 * t] = ex;        cur[2 * t] = ex;
    rp[2 * t + 1] = ex + c0; cur[2 * t + 1] = ex + c0;
    if (t == 1023) rp[2048] = val;   // == NNZ
}

// ---- stage 3: per-k hypernet eval, fold in x, write to CSR slot ----
__global__ __launch_bounds__(256) void compute_kernel(
    const float* __restrict__ z, const float* __restrict__ W,
    const float* __restrict__ bn, const int* __restrict__ in_idx,
    const int* __restrict__ out_idx, const float* __restrict__ xT,
    int* __restrict__ cur, float* __restrict__ E)
{
    __shared__ float zs[BATCH * ZDIM];   // 8 KB
    const int tid = threadIdx.x;
    {
        const float4* zg  = reinterpret_cast<const float4*>(z);
        float4*       zsv = reinterpret_cast<float4*>(zs);
        zsv[tid]       = zg[tid];
        zsv[tid + 256] = zg[tid + 256];
    }
    __syncthreads();

    const int k = blockIdx.x * 256 + tid;
    if (k >= NNZ) return;

    const int oi = out_idx[k];
    // Take the CSR slot early so the atomic's latency hides under the FMAs.
    const int pos = atomicAdd(&cur[oi], 1);
    const int ii  = in_idx[k];
    const float bk = bn[k];

    float w[ZDIM];
    #pragma unroll
    for (int j = 0; j < ZDIM; ++j)
        w[j] = W[(size_t)j * NNZ + k];   // coalesced across lanes

    const float4* zv = reinterpret_cast<const float4*>(zs);
    float4 ev[BATCH / 4];
    #pragma unroll
    for (int b = 0; b < BATCH; ++b) {
        float e = bk;
        #pragma unroll
        for (int j4 = 0; j4 < ZDIM / 4; ++j4) {
            const float4 zz = zv[b * (ZDIM / 4) + j4];   // LDS broadcast
            e = fmaf(zz.x, w[j4 * 4 + 0], e);
            e = fmaf(zz.y, w[j4 * 4 + 1], e);
            e = fmaf(zz.z, w[j4 * 4 + 2], e);
            e = fmaf(zz.w, w[j4 * 4 + 3], e);
        }
        reinterpret_cast<float*>(ev)[b] = e;
    }

    // Fold in x (contiguous 128B read) and store to slot (contiguous 128B write).
    const float4* xv = reinterpret_cast<const float4*>(xT + (size_t)ii * BATCH);
    float4*       Ep = reinterpret_cast<float4*>(E + (size_t)pos * BATCH);
    #pragma unroll
    for (int q = 0; q < BATCH / 4; ++q) {
        const float4 xx = xv[q];
        float4 t = ev[q];
        t.x *= xx.x; t.y *= xx.y; t.z *= xx.z; t.w *= xx.w;
        Ep[q] = t;
    }
}

// ---- stage 4: per-column segmented reduce, atomic-free ----
__global__ __launch_bounds__(256) void reduce_kernel(
    const float* __restrict__ E, const int* __restrict__ rp,
    float* __restrict__ out)
{
    const int wave = threadIdx.x >> 6;          // 4 waves/block
    const int lane = threadIdx.x & 63;
    const int o = blockIdx.x * 4 + wave;        // 512 blocks -> 2048 columns
    const int b = lane & 31;
    const int h = lane >> 5;
    const int s = rp[o], e = rp[o + 1];
    float sum = 0.f;
    for (int p = s + h; p < e; p += 2)          // 64 lanes read 256B contiguous
        sum += E[(size_t)p * BATCH + b];
    sum += __shfl_down(sum, 32);
    if (h == 0) out[b * OUT_DIM + o] = sum;
}

// ---- round-1 fallback (only if ws_size is too small) ----
__global__ __launch_bounds__(256) void hyper_scatter_kernel(
    const float* __restrict__ x, const float* __restrict__ z,
    const float* __restrict__ W, const float* __restrict__ bn,
    const int* __restrict__ in_idx, const int* __restrict__ out_idx,
    float* __restrict__ out)
{
    __shared__ float zs[BATCH * ZDIM];
    const int tid = threadIdx.x;
    {
        const float4* zg  = reinterpret_cast<const float4*>(z);
        float4*       zsv = reinterpret_cast<float4*>(zs);
        zsv[tid]       = zg[tid];
        zsv[tid + 256] = zg[tid + 256];
    }
    __syncthreads();
    const int k = blockIdx.x * 256 + tid;
    if (k >= NNZ) return;
    float w[ZDIM];
    #pragma unroll
    for (int j = 0; j < ZDIM; ++j) w[j] = W[(size_t)j * NNZ + k];
    const float bk = bn[k];
    const int ii = in_idx[k], oi = out_idx[k];
    const float4* zv = reinterpret_cast<const float4*>(zs);
    #pragma unroll
    for (int b = 0; b < BATCH; ++b) {
        float e = bk;
        #pragma unroll
        for (int j4 = 0; j4 < ZDIM / 4; ++j4) {
            const float4 zz = zv[b * (ZDIM / 4) + j4];
            e = fmaf(zz.x, w[j4 * 4 + 0], e);
            e = fmaf(zz.y, w[j4 * 4 + 1], e);
            e = fmaf(zz.z, w[j4 * 4 + 2], e);
            e = fmaf(zz.w, w[j4 * 4 + 3], e);
        }
        atomicAdd(&out[b * OUT_DIM + oi], e * x[b * IN_DIM + ii]);
    }
}

extern "C" void kernel_launch(void* const* d_in, const int* in_sizes, int n_in,
                              void* d_out, int out_size, void* d_ws, size_t ws_size,
                              hipStream_t stream) {
    const float* x       = (const float*)d_in[0];
    const float* z       = (const float*)d_in[1];
    const float* W       = (const float*)d_in[2];
    const float* bn      = (const float*)d_in[3];
    const int*   in_idx  = (const int*)d_in[4];
    const int*   out_idx = (const int*)d_in[5];
    float*       out     = (float*)d_out;

    if (ws_size < WS_NEEDED) {
        // Fallback: round-1 atomic scatter.
        hipMemsetAsync(out, 0, (size_t)BATCH * OUT_DIM * sizeof(float), stream);
        const int grid = (NNZ + 255) / 256;
        hyper_scatter_kernel<<<grid, 256, 0, stream>>>(x, z, W, bn, in_idx, out_idx, out);
        return;
    }

    char* ws = (char*)d_ws;
    int*   cnt = (int*)(ws + OFF_CNT);
    int*   rp  = (int*)(ws + OFF_RP);
    int*   cur = (int*)(ws + OFF_CUR);
    float* xT  = (float*)(ws + OFF_XT);
    float* E   = (float*)(ws + OFF_E);

    hipMemsetAsync(cnt, 0, 2048 * sizeof(int), stream);

    const int grid = (NNZ + 255) / 256;  // 820 blocks (covers the 65536 transpose too)
    hist_kernel<<<grid, 256, 0, stream>>>(out_idx, x, cnt, xT);
    scan_kernel<<<1, 1024, 0, stream>>>(cnt, rp, cur);
    compute_kernel<<<grid, 256, 0, stream>>>(z, W, bn, in_idx, out_idx, xT, cur, E);
    reduce_kernel<<<OUT_DIM / 4, 256, 0, stream>>>(E, rp, out);
}